// Round 2
// baseline (746.864 us; speedup 1.0000x reference)
//
#include <hip/hip_runtime.h>
#include <stdint.h>
#include <math.h>

// ---------------- constants ----------------
#define B_    4
#define L_    1024
#define H_    1024
#define NH_   16
#define M_    64
#define E_    24
#define R_    512
#define EMB_  768
#define BLK_  64
#define NCLS_ 97
#define NR_   2048        // B*R
#define KBIG_ 49152       // EMB*BLK  (bilinear GEMM K)

typedef unsigned short ushort_t;
typedef unsigned int uint_t;
typedef short bf16x8 __attribute__((ext_vector_type(8)));
typedef float f32x4  __attribute__((ext_vector_type(4)));

__device__ __forceinline__ float bf2f(ushort_t u) {
    return __uint_as_float(((unsigned)u) << 16);
}
__device__ __forceinline__ ushort_t f2bf_rne(float f) {
    unsigned u = __float_as_uint(f);
    return (ushort_t)((u + 0x7fffu + ((u >> 16) & 1u)) >> 16);
}

// ---------------- transpose + f32->bf16 convert ----------------
// in: f32 [batch][rows][cols] ; out: bf16 [batch][cols][rows]
__global__ __launch_bounds__(256) void k_transpose_cvt(
    const float* __restrict__ in, ushort_t* __restrict__ out, int rows, int cols)
{
    __shared__ float t[64][65];
    int batch = blockIdx.z;
    in  += (size_t)batch * rows * cols;
    out += (size_t)batch * rows * cols;
    int c0 = blockIdx.x * 64, r0 = blockIdx.y * 64;
    int tx = threadIdx.x & 63, ty = threadIdx.x >> 6;   // 64 x 4
#pragma unroll
    for (int dr = 0; dr < 64; dr += 4)
        t[dr + ty][tx] = in[(size_t)(r0 + dr + ty) * cols + (c0 + tx)];
    __syncthreads();
    int c = threadIdx.x >> 2;            // 64 output rows (cols of in)
    int rk = (threadIdx.x & 3) * 16;     // 16 consecutive r per thread
    ushort_t us[16];
#pragma unroll
    for (int q = 0; q < 16; q++) us[q] = f2bf_rne(t[rk + q][c]);
    ushort_t* op = &out[(size_t)(c0 + c) * rows + r0 + rk];
    *reinterpret_cast<int4*>(op)     = *reinterpret_cast<const int4*>(&us[0]);
    *reinterpret_cast<int4*>(op + 8) = *reinterpret_cast<const int4*>(&us[8]);
}

// ---------------- entity embedding: logsumexp over mentions ----------------
__global__ __launch_bounds__(256) void k_ent_emb(
    const float* __restrict__ ent_lhs, const int* __restrict__ labels,
    float* __restrict__ ent_emb)
{
    int b = blockIdx.x / E_, e = blockIdx.x % E_;
    __shared__ int list[M_];
    __shared__ int cnt;
    if (threadIdx.x == 0) cnt = 0;
    __syncthreads();
    if (threadIdx.x < M_ && labels[b * M_ + threadIdx.x] == e) {
        int p = atomicAdd(&cnt, 1);
        list[p] = threadIdx.x;
    }
    __syncthreads();
    int n = cnt;
    const float* base = ent_lhs + (size_t)b * M_ * H_;
    float* outp = ent_emb + ((size_t)b * E_ + e) * H_;
    for (int h = threadIdx.x; h < H_; h += blockDim.x) {
        if (n == 0) { outp[h] = 0.f; continue; }
        float mx = -1e30f;
        for (int i = 0; i < n; i++) mx = fmaxf(mx, base[(size_t)list[i] * H_ + h]);
        float s = 0.f;
        for (int i = 0; i < n; i++) s += __expf(base[(size_t)list[i] * H_ + h] - mx);
        outp[h] = mx + __logf(s);
    }
}

// ---------------- entity attention: mean over mentions ----------------
__global__ __launch_bounds__(256) void k_ent_attn(
    const float* __restrict__ attn, const int* __restrict__ labels,
    float* __restrict__ ent_attn)
{
    int idx = blockIdx.x;                 // b*E*NH + e*NH + nh
    int nh = idx % NH_;
    int be = idx / NH_;
    int e = be % E_, b = be / E_;
    __shared__ int list[M_];
    __shared__ int cnt;
    if (threadIdx.x == 0) cnt = 0;
    __syncthreads();
    if (threadIdx.x < M_ && labels[b * M_ + threadIdx.x] == e) {
        int p = atomicAdd(&cnt, 1);
        list[p] = threadIdx.x;
    }
    __syncthreads();
    int n = cnt;
    float inv = 1.f / fmaxf((float)n, 1.f);
    const float* base = attn + ((size_t)b * NH_ + nh) * M_ * L_;
    float* outp = ent_attn + (((size_t)b * E_ + e) * NH_ + nh) * L_;
    for (int l = threadIdx.x; l < L_; l += blockDim.x) {
        float s = 0.f;
        for (int i = 0; i < n; i++) s += base[(size_t)list[i] * L_ + l];
        outp[l] = s * inv;
    }
}

// ---------------- per-pair ht: mean over heads of ha*ta, row-normalized ----------------
__global__ __launch_bounds__(256) void k_ht(
    const float* __restrict__ ent_attn, const int* __restrict__ hts,
    ushort_t* __restrict__ ht_bf)
{
    int b = blockIdx.x / R_, r = blockIdx.x % R_;
    int h = hts[((size_t)b * R_ + r) * 2 + 0];
    int t = hts[((size_t)b * R_ + r) * 2 + 1];
    const float* ha = ent_attn + ((size_t)b * E_ + h) * NH_ * L_;
    const float* ta = ent_attn + ((size_t)b * E_ + t) * NH_ * L_;
    float vals[4];
    float local = 0.f;
#pragma unroll
    for (int p = 0; p < 4; p++) {
        int l = threadIdx.x + p * 256;
        float s = 0.f;
#pragma unroll
        for (int nh = 0; nh < NH_; nh++) s += ha[nh * L_ + l] * ta[nh * L_ + l];
        s *= (1.f / NH_);
        vals[p] = s;
        local += s;
    }
    __shared__ float red[4];
    float s = local;
#pragma unroll
    for (int off = 32; off > 0; off >>= 1) s += __shfl_down(s, off, 64);
    if ((threadIdx.x & 63) == 0) red[threadIdx.x >> 6] = s;
    __syncthreads();
    float tot = red[0] + red[1] + red[2] + red[3];
    float inv = 1.f / (tot + 1e-5f);
    ushort_t* outp = ht_bf + ((size_t)b * R_ + r) * L_;
#pragma unroll
    for (int p = 0; p < 4; p++) {
        int l = threadIdx.x + p * 256;
        outp[l] = f2bf_rne(vals[p] * inv);
    }
}

// ---------------- gather hs/ts into concat buffers (cols 0..1023) ----------------
__global__ __launch_bounds__(256) void k_gather(
    const float* __restrict__ ent_emb, const int* __restrict__ hts,
    ushort_t* __restrict__ A1, ushort_t* __restrict__ A2)
{
    int n = blockIdx.x;
    int b = n / R_, r = n % R_;
    int h = hts[((size_t)b * R_ + r) * 2 + 0];
    int t = hts[((size_t)b * R_ + r) * 2 + 1];
    const float* eh = ent_emb + ((size_t)b * E_ + h) * H_;
    const float* et = ent_emb + ((size_t)b * E_ + t) * H_;
    for (int i = threadIdx.x; i < H_; i += 256) {
        A1[(size_t)n * 2048 + i] = f2bf_rne(eh[i]);
        A2[(size_t)n * 2048 + i] = f2bf_rne(et[i]);
    }
}

// ---------------- generic bf16 MFMA GEMM (A[M][K] rm  x  Bt[N][K] rm) ----------------
// tile 128x128, 4 waves (2x2 of 64x64), BK=64. Epilogue bounces through LDS for
// 16B vector bf16 stores.
template <bool BIAS, bool TANH, bool DUAL>
__global__ __launch_bounds__(256) void k_gemm(
    const ushort_t* __restrict__ A, long sA, int lda,
    const ushort_t* __restrict__ Bt, long sB, int ldb,
    int K,
    const float* __restrict__ bias0, const float* __restrict__ bias1,
    ushort_t* __restrict__ C0, ushort_t* __restrict__ C1, long sC, int ldc)
{
    __shared__ ushort_t smem[2 * 128 * 72];   // As | Bs ; reused as 128x132 epilogue tile
    ushort_t* As = smem;
    ushort_t* Bs = smem + 128 * 72;
    const int tid = threadIdx.x;
    const int lane = tid & 63, wid = tid >> 6;
    const int wr = wid >> 1, wc = wid & 1;
    const int z = blockIdx.z;
    const int m0 = blockIdx.y * 128, n0 = blockIdx.x * 128;
    A  += (long)z * sA;
    Bt += (long)z * sB;

    const f32x4 zero = {0.f, 0.f, 0.f, 0.f};
    f32x4 acc[4][4];
#pragma unroll
    for (int i = 0; i < 4; i++)
#pragma unroll
        for (int j = 0; j < 4; j++) acc[i][j] = zero;

    const int mrow = wr * 64 + (lane & 15);
    const int nrow = wc * 64 + (lane & 15);
    const int koff = (lane >> 4) * 8;

    for (int k0 = 0; k0 < K; k0 += 64) {
        __syncthreads();
#pragma unroll
        for (int p = 0; p < 4; p++) {
            int idx = tid + p * 256;
            int row = idx >> 3, seg = idx & 7;
            *reinterpret_cast<int4*>(&As[row * 72 + seg * 8]) =
                *reinterpret_cast<const int4*>(&A[(long)(m0 + row) * lda + k0 + seg * 8]);
            *reinterpret_cast<int4*>(&Bs[row * 72 + seg * 8]) =
                *reinterpret_cast<const int4*>(&Bt[(long)(n0 + row) * ldb + k0 + seg * 8]);
        }
        __syncthreads();
#pragma unroll
        for (int ks = 0; ks < 2; ks++) {
            bf16x8 af[4], bfg[4];
#pragma unroll
            for (int mt = 0; mt < 4; mt++)
                af[mt] = *reinterpret_cast<const bf16x8*>(&As[(mrow + mt * 16) * 72 + ks * 32 + koff]);
#pragma unroll
            for (int nt = 0; nt < 4; nt++)
                bfg[nt] = *reinterpret_cast<const bf16x8*>(&Bs[(nrow + nt * 16) * 72 + ks * 32 + koff]);
#pragma unroll
            for (int mt = 0; mt < 4; mt++)
#pragma unroll
                for (int nt = 0; nt < 4; nt++)
                    acc[mt][nt] = __builtin_amdgcn_mfma_f32_16x16x32_bf16(
                        af[mt], bfg[nt], acc[mt][nt], 0, 0, 0);
        }
    }

    // epilogue: bias/tanh -> bf16 -> LDS (stride 132) -> 16B stores
    const float* bias = BIAS ? (z ? bias1 : bias0) : nullptr;
    __syncthreads();
#pragma unroll
    for (int mt = 0; mt < 4; mt++) {
#pragma unroll
        for (int nt = 0; nt < 4; nt++) {
#pragma unroll
            for (int rg = 0; rg < 4; rg++) {
                int row = wr * 64 + mt * 16 + (lane >> 4) * 4 + rg;   // 0..127 local
                int col = wc * 64 + nt * 16 + (lane & 15);            // 0..127 local
                float v = acc[mt][nt][rg];
                if (BIAS) v += bias[n0 + col];
                if (TANH) {
                    float vc = fminf(fmaxf(v, -15.f), 15.f);
                    float ex = __expf(2.f * vc);
                    v = (ex - 1.f) / (ex + 1.f);
                }
                smem[row * 132 + col] = f2bf_rne(v);
            }
        }
    }
    __syncthreads();
    {
        int row = tid >> 1, half = tid & 1;
        const ushort_t* src = &smem[row * 132 + half * 64];
        ushort_t* dst0 = &C0[(long)z * sC + (long)(m0 + row) * ldc + n0 + half * 64];
#pragma unroll
        for (int q = 0; q < 8; q++)
            *reinterpret_cast<int4*>(dst0 + q * 8) = *reinterpret_cast<const int4*>(src + q * 8);
        if (DUAL) {
            ushort_t* dst1 = &C1[(long)z * sC + (long)(m0 + row) * ldc + n0 + half * 64];
#pragma unroll
            for (int q = 0; q < 8; q++)
                *reinterpret_cast<int4*>(dst1 + q * 8) = *reinterpret_cast<const int4*>(src + q * 8);
        }
    }
}

// ---------------- bilinear GEMM, barrier-free reg-staged K-loop ----------------
// embeds[z] = (he (x) te outer-blocks) @ Wb, K-slice z. 768 blocks (96 spatial x 8 z),
// z = bid&7 (one 9.4 MB Wbt window per XCD; 16 blocks share each d0-window via L2).
//
// ROUND-2 CHANGE (evidence: depth-1 vmcnt prefetch AND -22pt VALUBusy both gave
// ZERO dur change -> neither latency nor VALU was the limit; the 2-barriers-per-i
// lockstep structure was ~3x the modeled critical path). So: NO per-i barriers.
// B-fragments are loaded straight into registers (8 global_load_dwordx4 per i per
// wave, L2-hot), 2-stage software-pipelined with named reg sets bA/bB (static
// indices only). LDS holds only HEs; __syncthreads only at kk-group boundaries
// (2-3 per kernel). Waves free-run; compiler emits counted vmcnt for plain loads.
// VGPR ~220 -> 2 waves/SIMD (launch_bounds(256,2)).
__global__ __launch_bounds__(256, 2) void k_bilinear(
    const ushort_t* __restrict__ he, const ushort_t* __restrict__ te,
    const ushort_t* __restrict__ Wbt, float* __restrict__ embedsN, int slices)
{
    __shared__ ushort_t HEs[128 * 72];
    const int tid = threadIdx.x;
    const int lane = tid & 63, wid = tid >> 6;
    const int wr = wid >> 1, wc = wid & 1;
    const int bid = blockIdx.x;
    const int z = bid & 7;                 // K-slice == XCD
    const int w = bid >> 3;
    const int d0 = (w % 6) * 128, n0 = (w / 6) * 128;
    const int c0 = z * 96, cend = c0 + 96;

    const f32x4 zero = {0.f, 0.f, 0.f, 0.f};
    f32x4 acc[4][4];
#pragma unroll
    for (int i = 0; i < 4; i++)
#pragma unroll
        for (int j = 0; j < 4; j++) acc[i][j] = zero;

    const int r15 = lane & 15;
    const int q4 = lane >> 4;
    const int mrow = wr * 64 + r15;        // A-frag row (n of embeds)
    const int koff = q4 * 8;

    // per-wave global row pointers for B fragments (rows = d output dim)
    const ushort_t* Brow0 = Wbt + (long)(d0 + wc * 64 + 0 * 16 + r15) * KBIG_ + koff;
    const ushort_t* Brow1 = Wbt + (long)(d0 + wc * 64 + 1 * 16 + r15) * KBIG_ + koff;
    const ushort_t* Brow2 = Wbt + (long)(d0 + wc * 64 + 2 * 16 + r15) * KBIG_ + koff;
    const ushort_t* Brow3 = Wbt + (long)(d0 + wc * 64 + 3 * 16 + r15) * KBIG_ + koff;

    uint4 bA[8], bB[8];
    float tf[4][2][8];

    // loadB: B-frags for column col of the outer product (K=64 contraction over q)
    auto loadB = [&](uint4* bx, int col) {
        const long cb = (long)col * 64;
#pragma unroll
        for (int ks = 0; ks < 2; ks++) {
            bx[ks * 4 + 0] = *reinterpret_cast<const uint4*>(Brow0 + cb + ks * 32);
            bx[ks * 4 + 1] = *reinterpret_cast<const uint4*>(Brow1 + cb + ks * 32);
            bx[ks * 4 + 2] = *reinterpret_cast<const uint4*>(Brow2 + cb + ks * 32);
            bx[ks * 4 + 3] = *reinterpret_cast<const uint4*>(Brow3 + cb + ks * 32);
        }
    };
    // compute: af = te_frag * he_scalar (f32 mul + RNE cvt), 32 MFMA
    auto compute = [&](const uint4* bx, int i) {
#pragma unroll
        for (int mt = 0; mt < 4; mt++) {
            float hf = bf2f(HEs[(mrow + mt * 16) * 72 + i]);
#pragma unroll
            for (int ks = 0; ks < 2; ks++) {
                union { __bf16 h[8]; bf16x8 v; } af;
#pragma unroll
                for (int qq = 0; qq < 8; qq++)
                    af.h[qq] = (__bf16)(tf[mt][ks][qq] * hf);
#pragma unroll
                for (int nt = 0; nt < 4; nt++)
                    acc[mt][nt] = __builtin_amdgcn_mfma_f32_16x16x32_bf16(
                        af.v, *reinterpret_cast<const bf16x8*>(&bx[ks * 4 + nt]),
                        acc[mt][nt], 0, 0, 0);
            }
        }
    };

    int c = c0;
    while (c < cend) {
        const int kk = c >> 6;
        const int i0 = c & 63;
        const int i1 = min(64, i0 + (cend - c));   // i1-i0 is 32 or 64 (even)

        // stage he[n0..n0+128][kk*64..+64] into LDS (row-major, stride 72)
        __syncthreads();   // prev group done reading HEs
#pragma unroll
        for (int p = 0; p < 4; p++) {
            int idx = tid + p * 256;
            int row = idx >> 3, seg = idx & 7;
            *reinterpret_cast<int4*>(&HEs[row * 72 + seg * 8]) =
                *reinterpret_cast<const int4*>(&he[(long)(n0 + row) * EMB_ + kk * 64 + seg * 8]);
        }
        __syncthreads();

        // te fragments for this kk-group: global -> f32 registers (reused over all i)
#pragma unroll
        for (int mt = 0; mt < 4; mt++)
#pragma unroll
            for (int ks = 0; ks < 2; ks++) {
                uint4 t = *reinterpret_cast<const uint4*>(
                    &te[(long)(n0 + mrow + mt * 16) * EMB_ + kk * 64 + ks * 32 + koff]);
                const ushort_t* ts = reinterpret_cast<const ushort_t*>(&t);
#pragma unroll
                for (int qq = 0; qq < 8; qq++) tf[mt][ks][qq] = bf2f(ts[qq]);
            }

        // 2-stage software pipeline, no barriers: waves free-run
        loadB(bA, kk * 64 + i0);
        for (int i = i0; i < i1; i += 2) {
            loadB(bB, kk * 64 + i + 1);
            compute(bA, i);
            if (i + 2 < i1) loadB(bA, kk * 64 + i + 2);
            compute(bB, i + 1);
        }
        c += (i1 - i0);
    }

    // epilogue: plain fp32 stores into slice z (slices==8), else atomic into slice 0
    float* outp = embedsN + (slices == 8 ? (long)z * NR_ * EMB_ : 0l);
    const bool plain = (slices == 8);
#pragma unroll
    for (int mt = 0; mt < 4; mt++)
#pragma unroll
        for (int nt = 0; nt < 4; nt++)
#pragma unroll
            for (int rg = 0; rg < 4; rg++) {
                int n = n0 + wr * 64 + mt * 16 + q4 * 4 + rg;
                int d = d0 + wc * 64 + nt * 16 + r15;
                if (plain) outp[(long)n * EMB_ + d] = acc[mt][nt][rg];
                else       atomicAdd(&outp[(long)n * EMB_ + d], acc[mt][nt][rg]);
            }
}

// ---------------- final head: out = (sum_z embeds + bb) @ Wc + bc  (fp32) ----------------
__global__ __launch_bounds__(128) void k_final(
    const float* __restrict__ embedsN, int nz, const float* __restrict__ bb,
    const float* __restrict__ Wc, const float* __restrict__ bc,
    float* __restrict__ out)
{
    int n = blockIdx.x;
    __shared__ float row[EMB_];
    for (int i = threadIdx.x; i < EMB_; i += 128) {
        float s = bb[i];
        for (int zz = 0; zz < nz; zz++)
            s += embedsN[(size_t)zz * NR_ * EMB_ + (size_t)n * EMB_ + i];
        row[i] = s;
    }
    __syncthreads();
    int j = threadIdx.x;
    if (j < NCLS_) {
        float s = bc[j];
#pragma unroll 8
        for (int d = 0; d < EMB_; d++) s += row[d] * Wc[d * NCLS_ + j];
        out[(size_t)n * NCLS_ + j] = s;
    }
}

// ---------------- launcher ----------------
extern "C" void kernel_launch(void* const* d_in, const int* in_sizes, int n_in,
                              void* d_out, int out_size, void* d_ws, size_t ws_size,
                              hipStream_t stream)
{
    (void)in_sizes; (void)n_in; (void)out_size;
    const float* seq    = (const float*)d_in[0];
    const float* entl   = (const float*)d_in[1];
    const float* attn   = (const float*)d_in[2];
    const int*   labels = (const int*)d_in[3];
    const int*   hts    = (const int*)d_in[4];
    const float* Wh     = (const float*)d_in[5];
    const float* bh     = (const float*)d_in[6];
    const float* Wt     = (const float*)d_in[7];
    const float* bt     = (const float*)d_in[8];
    const float* Wb     = (const float*)d_in[9];
    const float* bb     = (const float*)d_in[10];
    const float* Wc     = (const float*)d_in[11];
    const float* bc     = (const float*)d_in[12];
    float* out = (float*)d_out;

    char* ws = (char*)d_ws;
    size_t off = 0;
    auto alloc = [&](size_t bytes) -> char* {
        char* p = ws + off;
        off += (bytes + 255) & ~(size_t)255;
        return p;
    };
    float*    ent_emb  = (float*)alloc((size_t)B_ * E_ * H_ * 4);
    float*    ent_attn = (float*)alloc((size_t)B_ * E_ * NH_ * L_ * 4);
    ushort_t* ht_bf    = (ushort_t*)alloc((size_t)B_ * R_ * L_ * 2);
    ushort_t* seq_t    = (ushort_t*)alloc((size_t)B_ * H_ * L_ * 2);
    ushort_t* A1       = (ushort_t*)alloc((size_t)NR_ * 2048 * 2);   // [hs | rel]
    ushort_t* A2       = (ushort_t*)alloc((size_t)NR_ * 2048 * 2);   // [ts | rel] (adjacent)
    ushort_t* Whb      = (ushort_t*)alloc((size_t)EMB_ * 2048 * 2);  // Wh^T bf16
    ushort_t* Wtb      = (ushort_t*)alloc((size_t)EMB_ * 2048 * 2);  // adjacent to Whb
    ushort_t* he_bf    = (ushort_t*)alloc((size_t)NR_ * EMB_ * 2);
    ushort_t* te_bf    = (ushort_t*)alloc((size_t)NR_ * EMB_ * 2);   // adjacent to he_bf
    ushort_t* Wbt      = (ushort_t*)alloc((size_t)EMB_ * KBIG_ * 2); // Wb^T bf16 [768][49152]

    const size_t slice_b = (size_t)NR_ * EMB_ * 4;
    int slices = (ws_size >= off + 8 * slice_b) ? 8 : 1;
    float* embedsN = (float*)alloc((size_t)slices * slice_b);

    // 1) transposed bf16 copies of weights / seq
    k_transpose_cvt<<<dim3(H_ / 64, L_ / 64, B_), 256, 0, stream>>>(seq, seq_t, L_, H_);
    k_transpose_cvt<<<dim3(EMB_ / 64, 2048 / 64, 1), 256, 0, stream>>>(Wh, Whb, 2048, EMB_);
    k_transpose_cvt<<<dim3(EMB_ / 64, 2048 / 64, 1), 256, 0, stream>>>(Wt, Wtb, 2048, EMB_);
    k_transpose_cvt<<<dim3(EMB_ / 64, KBIG_ / 64, 1), 256, 0, stream>>>(Wb, Wbt, KBIG_, EMB_);

    // 2) entity aggregation
    k_ent_emb<<<B_ * E_, 256, 0, stream>>>(entl, labels, ent_emb);
    k_ent_attn<<<B_ * E_ * NH_, 256, 0, stream>>>(attn, labels, ent_attn);

    // 3) pair attention rows + gathers
    k_ht<<<NR_, 256, 0, stream>>>(ent_attn, hts, ht_bf);
    k_gather<<<NR_, 256, 0, stream>>>(ent_emb, hts, A1, A2);

    // 4) rel = ht @ seq  (batched over B), written bf16 into cols 1024.. of A1 and A2
    k_gemm<false, false, true><<<dim3(H_ / 128, R_ / 128, B_), 256, 0, stream>>>(
        ht_bf, (long)R_ * L_, L_,
        seq_t, (long)H_ * L_, L_,
        L_, nullptr, nullptr,
        A1 + 1024, A2 + 1024, (long)R_ * 2048, 2048);

    // 5) he = tanh(A1 @ Wh + bh), te = tanh(A2 @ Wt + bt)   (z selects the pair)
    k_gemm<true, true, false><<<dim3(EMB_ / 128, NR_ / 128, 2), 256, 0, stream>>>(
        A1, (long)NR_ * 2048, 2048,
        Whb, (long)EMB_ * 2048, 2048,
        2048, bh, bt,
        he_bf, nullptr, (long)NR_ * EMB_, EMB_);

    // 6) embeds = bl @ Wb  (barrier-free reg-staged K-loop; 8 K-slices XCD-mapped)
    if (slices == 1)
        (void)hipMemsetAsync(embedsN, 0, slice_b, stream);
    k_bilinear<<<768, 256, 0, stream>>>(he_bf, te_bf, Wbt, embedsN, slices);

    // 7) out = (sum_z embeds + bb) @ Wc + bc   (fp32)
    k_final<<<NR_, 128, 0, stream>>>(embedsN, slices, bb, Wc, bc, out);
}

// Round 5
// 635.364 us; speedup vs baseline: 1.1755x; 1.1755x over previous
//
#include <hip/hip_runtime.h>
#include <stdint.h>
#include <math.h>

// ---------------- constants ----------------
#define B_    4
#define L_    1024
#define H_    1024
#define NH_   16
#define M_    64
#define E_    24
#define R_    512
#define EMB_  768
#define BLK_  64
#define NCLS_ 97
#define NR_   2048        // B*R
#define KBIG_ 49152       // EMB*BLK  (bilinear GEMM K)

typedef unsigned short ushort_t;
typedef unsigned int uint_t;
typedef short bf16x8 __attribute__((ext_vector_type(8)));
typedef float f32x4  __attribute__((ext_vector_type(4)));

__device__ __forceinline__ float bf2f(ushort_t u) {
    return __uint_as_float(((unsigned)u) << 16);
}
__device__ __forceinline__ ushort_t f2bf_rne(float f) {
    unsigned u = __float_as_uint(f);
    return (ushort_t)((u + 0x7fffu + ((u >> 16) & 1u)) >> 16);
}
// async global->LDS 16B/lane; lds base must be wave-uniform (lane lands at +lane*16)
__device__ __forceinline__ void cp16(const void* g, void* l) {
    __builtin_amdgcn_global_load_lds(
        (const __attribute__((address_space(1))) void*)g,
        (__attribute__((address_space(3))) void*)l, 16, 0, 0);
}

// ---------------- transpose + f32->bf16 convert ----------------
// in: f32 [batch][rows][cols] ; out: bf16 [batch][cols][rows]
__global__ __launch_bounds__(256) void k_transpose_cvt(
    const float* __restrict__ in, ushort_t* __restrict__ out, int rows, int cols)
{
    __shared__ float t[64][65];
    int batch = blockIdx.z;
    in  += (size_t)batch * rows * cols;
    out += (size_t)batch * rows * cols;
    int c0 = blockIdx.x * 64, r0 = blockIdx.y * 64;
    int tx = threadIdx.x & 63, ty = threadIdx.x >> 6;   // 64 x 4
#pragma unroll
    for (int dr = 0; dr < 64; dr += 4)
        t[dr + ty][tx] = in[(size_t)(r0 + dr + ty) * cols + (c0 + tx)];
    __syncthreads();
    int c = threadIdx.x >> 2;            // 64 output rows (cols of in)
    int rk = (threadIdx.x & 3) * 16;     // 16 consecutive r per thread
    ushort_t us[16];
#pragma unroll
    for (int q = 0; q < 16; q++) us[q] = f2bf_rne(t[rk + q][c]);
    ushort_t* op = &out[(size_t)(c0 + c) * rows + r0 + rk];
    *reinterpret_cast<int4*>(op)     = *reinterpret_cast<const int4*>(&us[0]);
    *reinterpret_cast<int4*>(op + 8) = *reinterpret_cast<const int4*>(&us[8]);
}

// ---------------- entity embedding: logsumexp over mentions ----------------
__global__ __launch_bounds__(256) void k_ent_emb(
    const float* __restrict__ ent_lhs, const int* __restrict__ labels,
    float* __restrict__ ent_emb)
{
    int b = blockIdx.x / E_, e = blockIdx.x % E_;
    __shared__ int list[M_];
    __shared__ int cnt;
    if (threadIdx.x == 0) cnt = 0;
    __syncthreads();
    if (threadIdx.x < M_ && labels[b * M_ + threadIdx.x] == e) {
        int p = atomicAdd(&cnt, 1);
        list[p] = threadIdx.x;
    }
    __syncthreads();
    int n = cnt;
    const float* base = ent_lhs + (size_t)b * M_ * H_;
    float* outp = ent_emb + ((size_t)b * E_ + e) * H_;
    for (int h = threadIdx.x; h < H_; h += blockDim.x) {
        if (n == 0) { outp[h] = 0.f; continue; }
        float mx = -1e30f;
        for (int i = 0; i < n; i++) mx = fmaxf(mx, base[(size_t)list[i] * H_ + h]);
        float s = 0.f;
        for (int i = 0; i < n; i++) s += __expf(base[(size_t)list[i] * H_ + h] - mx);
        outp[h] = mx + __logf(s);
    }
}

// ---------------- entity attention: mean over mentions ----------------
__global__ __launch_bounds__(256) void k_ent_attn(
    const float* __restrict__ attn, const int* __restrict__ labels,
    float* __restrict__ ent_attn)
{
    int idx = blockIdx.x;                 // b*E*NH + e*NH + nh
    int nh = idx % NH_;
    int be = idx / NH_;
    int e = be % E_, b = be / E_;
    __shared__ int list[M_];
    __shared__ int cnt;
    if (threadIdx.x == 0) cnt = 0;
    __syncthreads();
    if (threadIdx.x < M_ && labels[b * M_ + threadIdx.x] == e) {
        int p = atomicAdd(&cnt, 1);
        list[p] = threadIdx.x;
    }
    __syncthreads();
    int n = cnt;
    float inv = 1.f / fmaxf((float)n, 1.f);
    const float* base = attn + ((size_t)b * NH_ + nh) * M_ * L_;
    float* outp = ent_attn + (((size_t)b * E_ + e) * NH_ + nh) * L_;
    for (int l = threadIdx.x; l < L_; l += blockDim.x) {
        float s = 0.f;
        for (int i = 0; i < n; i++) s += base[(size_t)list[i] * L_ + l];
        outp[l] = s * inv;
    }
}

// ---------------- per-pair ht: mean over heads of ha*ta, row-normalized ----------------
__global__ __launch_bounds__(256) void k_ht(
    const float* __restrict__ ent_attn, const int* __restrict__ hts,
    ushort_t* __restrict__ ht_bf)
{
    int b = blockIdx.x / R_, r = blockIdx.x % R_;
    int h = hts[((size_t)b * R_ + r) * 2 + 0];
    int t = hts[((size_t)b * R_ + r) * 2 + 1];
    const float* ha = ent_attn + ((size_t)b * E_ + h) * NH_ * L_;
    const float* ta = ent_attn + ((size_t)b * E_ + t) * NH_ * L_;
    float vals[4];
    float local = 0.f;
#pragma unroll
    for (int p = 0; p < 4; p++) {
        int l = threadIdx.x + p * 256;
        float s = 0.f;
#pragma unroll
        for (int nh = 0; nh < NH_; nh++) s += ha[nh * L_ + l] * ta[nh * L_ + l];
        s *= (1.f / NH_);
        vals[p] = s;
        local += s;
    }
    __shared__ float red[4];
    float s = local;
#pragma unroll
    for (int off = 32; off > 0; off >>= 1) s += __shfl_down(s, off, 64);
    if ((threadIdx.x & 63) == 0) red[threadIdx.x >> 6] = s;
    __syncthreads();
    float tot = red[0] + red[1] + red[2] + red[3];
    float inv = 1.f / (tot + 1e-5f);
    ushort_t* outp = ht_bf + ((size_t)b * R_ + r) * L_;
#pragma unroll
    for (int p = 0; p < 4; p++) {
        int l = threadIdx.x + p * 256;
        outp[l] = f2bf_rne(vals[p] * inv);
    }
}

// ---------------- gather hs/ts into concat buffers (cols 0..1023) ----------------
__global__ __launch_bounds__(256) void k_gather(
    const float* __restrict__ ent_emb, const int* __restrict__ hts,
    ushort_t* __restrict__ A1, ushort_t* __restrict__ A2)
{
    int n = blockIdx.x;
    int b = n / R_, r = n % R_;
    int h = hts[((size_t)b * R_ + r) * 2 + 0];
    int t = hts[((size_t)b * R_ + r) * 2 + 1];
    const float* eh = ent_emb + ((size_t)b * E_ + h) * H_;
    const float* et = ent_emb + ((size_t)b * E_ + t) * H_;
    for (int i = threadIdx.x; i < H_; i += 256) {
        A1[(size_t)n * 2048 + i] = f2bf_rne(eh[i]);
        A2[(size_t)n * 2048 + i] = f2bf_rne(et[i]);
    }
}

// ---------------- generic bf16 MFMA GEMM (A[M][K] rm  x  Bt[N][K] rm) ----------------
// tile 128x128, 4 waves (2x2 of 64x64), BK=64. Epilogue bounces through LDS for
// 16B vector bf16 stores.
template <bool BIAS, bool TANH, bool DUAL>
__global__ __launch_bounds__(256) void k_gemm(
    const ushort_t* __restrict__ A, long sA, int lda,
    const ushort_t* __restrict__ Bt, long sB, int ldb,
    int K,
    const float* __restrict__ bias0, const float* __restrict__ bias1,
    ushort_t* __restrict__ C0, ushort_t* __restrict__ C1, long sC, int ldc)
{
    __shared__ ushort_t smem[2 * 128 * 72];   // As | Bs ; reused as 128x132 epilogue tile
    ushort_t* As = smem;
    ushort_t* Bs = smem + 128 * 72;
    const int tid = threadIdx.x;
    const int lane = tid & 63, wid = tid >> 6;
    const int wr = wid >> 1, wc = wid & 1;
    const int z = blockIdx.z;
    const int m0 = blockIdx.y * 128, n0 = blockIdx.x * 128;
    A  += (long)z * sA;
    Bt += (long)z * sB;

    const f32x4 zero = {0.f, 0.f, 0.f, 0.f};
    f32x4 acc[4][4];
#pragma unroll
    for (int i = 0; i < 4; i++)
#pragma unroll
        for (int j = 0; j < 4; j++) acc[i][j] = zero;

    const int mrow = wr * 64 + (lane & 15);
    const int nrow = wc * 64 + (lane & 15);
    const int koff = (lane >> 4) * 8;

    for (int k0 = 0; k0 < K; k0 += 64) {
        __syncthreads();
#pragma unroll
        for (int p = 0; p < 4; p++) {
            int idx = tid + p * 256;
            int row = idx >> 3, seg = idx & 7;
            *reinterpret_cast<int4*>(&As[row * 72 + seg * 8]) =
                *reinterpret_cast<const int4*>(&A[(long)(m0 + row) * lda + k0 + seg * 8]);
            *reinterpret_cast<int4*>(&Bs[row * 72 + seg * 8]) =
                *reinterpret_cast<const int4*>(&Bt[(long)(n0 + row) * ldb + k0 + seg * 8]);
        }
        __syncthreads();
#pragma unroll
        for (int ks = 0; ks < 2; ks++) {
            bf16x8 af[4], bfg[4];
#pragma unroll
            for (int mt = 0; mt < 4; mt++)
                af[mt] = *reinterpret_cast<const bf16x8*>(&As[(mrow + mt * 16) * 72 + ks * 32 + koff]);
#pragma unroll
            for (int nt = 0; nt < 4; nt++)
                bfg[nt] = *reinterpret_cast<const bf16x8*>(&Bs[(nrow + nt * 16) * 72 + ks * 32 + koff]);
#pragma unroll
            for (int mt = 0; mt < 4; mt++)
#pragma unroll
                for (int nt = 0; nt < 4; nt++)
                    acc[mt][nt] = __builtin_amdgcn_mfma_f32_16x16x32_bf16(
                        af[mt], bfg[nt], acc[mt][nt], 0, 0, 0);
        }
    }

    // epilogue: bias/tanh -> bf16 -> LDS (stride 132) -> 16B stores
    const float* bias = BIAS ? (z ? bias1 : bias0) : nullptr;
    __syncthreads();
#pragma unroll
    for (int mt = 0; mt < 4; mt++) {
#pragma unroll
        for (int nt = 0; nt < 4; nt++) {
#pragma unroll
            for (int rg = 0; rg < 4; rg++) {
                int row = wr * 64 + mt * 16 + (lane >> 4) * 4 + rg;   // 0..127 local
                int col = wc * 64 + nt * 16 + (lane & 15);            // 0..127 local
                float v = acc[mt][nt][rg];
                if (BIAS) v += bias[n0 + col];
                if (TANH) {
                    float vc = fminf(fmaxf(v, -15.f), 15.f);
                    float ex = __expf(2.f * vc);
                    v = (ex - 1.f) / (ex + 1.f);
                }
                smem[row * 132 + col] = f2bf_rne(v);
            }
        }
    }
    __syncthreads();
    {
        int row = tid >> 1, half = tid & 1;
        const ushort_t* src = &smem[row * 132 + half * 64];
        ushort_t* dst0 = &C0[(long)z * sC + (long)(m0 + row) * ldc + n0 + half * 64];
#pragma unroll
        for (int q = 0; q < 8; q++)
            *reinterpret_cast<int4*>(dst0 + q * 8) = *reinterpret_cast<const int4*>(src + q * 8);
        if (DUAL) {
            ushort_t* dst1 = &C1[(long)z * sC + (long)(m0 + row) * ldc + n0 + half * 64];
#pragma unroll
            for (int q = 0; q < 8; q++)
                *reinterpret_cast<int4*>(dst1 + q * 8) = *reinterpret_cast<const int4*>(src + q * 8);
        }
    }
}

// ---------------- bilinear GEMM, single-__syncthreads-per-i K-loop ----------------
// embeds[z] = (he (x) te outer-blocks) @ Wb, K-slice z. 768 blocks (96 spatial x 8 z),
// z = bid&7 (one 9.4 MB Wbt window per XCD). LDS-staged B (global_load_lds) proven
// essential (R2: reg-staged = -60%).
//
// ROUND-5: same barrier-count hypothesis as R3/R4 (which never ran -- container
// failed twice; possibly infra, possibly the raw s_barrier+inline-vmcnt loop).
// SAFE implementation using ONLY __syncthreads():
//   per i: [__syncthreads (drains vmcnt+lgkm, converges);
//           issue cp16(i+1)->buf^1;  compute tile i from buf[cur]]
// Tile i+1's loads are in flight across the whole compute phase (same depth as
// R1) but there is ONE barrier per i instead of two: 96 convergences vs 192.
// Correctness: buf^1 was last read at i-1, before this barrier; tile-i loads
// were issued at i-1 and are drained by this barrier's implicit vmcnt(0).
// Deadlock-free by construction (uniform control flow, standard barrier).
// LDS 51.2 KB (HEs 18.4 + 2x16 Bsh) -> 3 blocks/CU, identical to R1.
__global__ __launch_bounds__(256, 3) void k_bilinear(
    const ushort_t* __restrict__ he, const ushort_t* __restrict__ te,
    const ushort_t* __restrict__ Wbt, float* __restrict__ embedsN, int slices)
{
    __shared__ ushort_t HEs[128 * 72];
    __shared__ ushort_t Bsh[2][128 * 64];  // ring-2 B-tile, unpadded
    const int tid = threadIdx.x;
    const int lane = tid & 63, wid = tid >> 6;
    const int wr = wid >> 1, wc = wid & 1;
    const int bid = blockIdx.x;
    const int z = bid & 7;                 // K-slice == XCD
    const int w = bid >> 3;
    const int d0 = (w % 6) * 128, n0 = (w / 6) * 128;
    const int c0 = z * 96, cend = c0 + 96;

    const f32x4 zero = {0.f, 0.f, 0.f, 0.f};
    f32x4 acc[4][4];
#pragma unroll
    for (int i = 0; i < 4; i++)
#pragma unroll
        for (int j = 0; j < 4; j++) acc[i][j] = zero;

    const int r15 = lane & 15;
    const int q4 = lane >> 4;
    const int mrow = wr * 64 + r15;        // A-frag row (n of embeds)
    const int koff = q4 * 8;

    // per-lane global base for B staging: lane covers row wid*32 + (lane>>3),
    // seg slot (lane&7) holds global seg (lane&7)^((lane>>3)&7)  [xor swizzle]
    const ushort_t* Pg = Wbt
        + (long)(d0 + wid * 32 + (lane >> 3)) * KBIG_
        + ((lane & 7) ^ ((lane >> 3) & 7)) * 8;

    int c = c0;
    while (c < cend) {
        const int kk = c >> 6;
        const int i0 = c & 63;
        const int i1 = min(64, i0 + (cend - c));

        __syncthreads();   // prev group fully done reading HEs / Bsh

        // issue tile i0 into buf0 (latency overlaps HEs staging + te loads)
        {
            const ushort_t* g = Pg + (long)(kk * 64 + i0) * 64;
            ushort_t* Pl = Bsh[0] + wid * 2048;
            cp16(g,              Pl);
            cp16(g +  8 * KBIG_, Pl + 512);
            cp16(g + 16 * KBIG_, Pl + 1024);
            cp16(g + 24 * KBIG_, Pl + 1536);
        }

        // stage he[n0..n0+128][kk*64..+64] into LDS (row-major, stride 72)
#pragma unroll
        for (int p = 0; p < 4; p++) {
            int idx = tid + p * 256;
            int row = idx >> 3, seg = idx & 7;
            *reinterpret_cast<int4*>(&HEs[row * 72 + seg * 8]) =
                *reinterpret_cast<const int4*>(&he[(long)(n0 + row) * EMB_ + kk * 64 + seg * 8]);
        }

        // te fragments for this kk-group: global -> f32 registers (reused over all i)
        float tf[4][2][8];
#pragma unroll
        for (int mt = 0; mt < 4; mt++)
#pragma unroll
            for (int ks = 0; ks < 2; ks++) {
                uint4 t = *reinterpret_cast<const uint4*>(
                    &te[(long)(n0 + mrow + mt * 16) * EMB_ + kk * 64 + ks * 32 + koff]);
                const ushort_t* ts = reinterpret_cast<const ushort_t*>(&t);
#pragma unroll
                for (int qq = 0; qq < 8; qq++) tf[mt][ks][qq] = bf2f(ts[qq]);
            }

        int cur = 0;
        for (int i = i0; i < i1; i++) {
            // ONE barrier per i: implicit vmcnt(0)+lgkmcnt(0) drains tile-i
            // loads (issued last iteration) and HEs writes; convergence makes
            // all waves' LDS writes mutually visible.
            __syncthreads();

            // issue tile i+1 into buf^1 (last read at compute(i-1), which
            // precedes this barrier on every wave)
            if (i + 1 < i1) {
                const ushort_t* g = Pg + (long)(kk * 64 + i + 1) * 64;
                ushort_t* Pl = Bsh[cur ^ 1] + wid * 2048;
                cp16(g,              Pl);
                cp16(g +  8 * KBIG_, Pl + 512);
                cp16(g + 16 * KBIG_, Pl + 1024);
                cp16(g + 24 * KBIG_, Pl + 1536);
            }

            const ushort_t* Bcur = Bsh[cur];
            bf16x8 bfr[2][4];
#pragma unroll
            for (int ks = 0; ks < 2; ks++) {
                const int segoff = (((ks * 4 + q4) ^ (r15 & 7)) * 8);
#pragma unroll
                for (int nt = 0; nt < 4; nt++)
                    bfr[ks][nt] = *reinterpret_cast<const bf16x8*>(
                        &Bcur[(wc * 64 + nt * 16 + r15) * 64 + segoff]);
            }
#pragma unroll
            for (int mt = 0; mt < 4; mt++) {
                float hf = bf2f(HEs[(mrow + mt * 16) * 72 + i]);
#pragma unroll
                for (int ks = 0; ks < 2; ks++) {
                    union { __bf16 h[8]; bf16x8 v; } af;
#pragma unroll
                    for (int qq = 0; qq < 8; qq++)
                        af.h[qq] = (__bf16)(tf[mt][ks][qq] * hf);
#pragma unroll
                    for (int nt = 0; nt < 4; nt++)
                        acc[mt][nt] = __builtin_amdgcn_mfma_f32_16x16x32_bf16(
                            af.v, bfr[ks][nt], acc[mt][nt], 0, 0, 0);
                }
            }
            cur ^= 1;
        }
        c += (i1 - i0);
    }

    // epilogue: plain fp32 stores into slice z (slices==8), else atomic into slice 0
    float* outp = embedsN + (slices == 8 ? (long)z * NR_ * EMB_ : 0l);
    const bool plain = (slices == 8);
#pragma unroll
    for (int mt = 0; mt < 4; mt++)
#pragma unroll
        for (int nt = 0; nt < 4; nt++)
#pragma unroll
            for (int rg = 0; rg < 4; rg++) {
                int n = n0 + wr * 64 + mt * 16 + q4 * 4 + rg;
                int d = d0 + wc * 64 + nt * 16 + r15;
                if (plain) outp[(long)n * EMB_ + d] = acc[mt][nt][rg];
                else       atomicAdd(&outp[(long)n * EMB_ + d], acc[mt][nt][rg]);
            }
}

// ---------------- final head: out = (sum_z embeds + bb) @ Wc + bc  (fp32) ----------------
__global__ __launch_bounds__(128) void k_final(
    const float* __restrict__ embedsN, int nz, const float* __restrict__ bb,
    const float* __restrict__ Wc, const float* __restrict__ bc,
    float* __restrict__ out)
{
    int n = blockIdx.x;
    __shared__ float row[EMB_];
    for (int i = threadIdx.x; i < EMB_; i += 128) {
        float s = bb[i];
        for (int zz = 0; zz < nz; zz++)
            s += embedsN[(size_t)zz * NR_ * EMB_ + (size_t)n * EMB_ + i];
        row[i] = s;
    }
    __syncthreads();
    int j = threadIdx.x;
    if (j < NCLS_) {
        float s = bc[j];
#pragma unroll 8
        for (int d = 0; d < EMB_; d++) s += row[d] * Wc[d * NCLS_ + j];
        out[(size_t)n * NCLS_ + j] = s;
    }
}

// ---------------- launcher ----------------
extern "C" void kernel_launch(void* const* d_in, const int* in_sizes, int n_in,
                              void* d_out, int out_size, void* d_ws, size_t ws_size,
                              hipStream_t stream)
{
    (void)in_sizes; (void)n_in; (void)out_size;
    const float* seq    = (const float*)d_in[0];
    const float* entl   = (const float*)d_in[1];
    const float* attn   = (const float*)d_in[2];
    const int*   labels = (const int*)d_in[3];
    const int*   hts    = (const int*)d_in[4];
    const float* Wh     = (const float*)d_in[5];
    const float* bh     = (const float*)d_in[6];
    const float* Wt     = (const float*)d_in[7];
    const float* bt     = (const float*)d_in[8];
    const float* Wb     = (const float*)d_in[9];
    const float* bb     = (const float*)d_in[10];
    const float* Wc     = (const float*)d_in[11];
    const float* bc     = (const float*)d_in[12];
    float* out = (float*)d_out;

    char* ws = (char*)d_ws;
    size_t off = 0;
    auto alloc = [&](size_t bytes) -> char* {
        char* p = ws + off;
        off += (bytes + 255) & ~(size_t)255;
        return p;
    };
    float*    ent_emb  = (float*)alloc((size_t)B_ * E_ * H_ * 4);
    float*    ent_attn = (float*)alloc((size_t)B_ * E_ * NH_ * L_ * 4);
    ushort_t* ht_bf    = (ushort_t*)alloc((size_t)B_ * R_ * L_ * 2);
    ushort_t* seq_t    = (ushort_t*)alloc((size_t)B_ * H_ * L_ * 2);
    ushort_t* A1       = (ushort_t*)alloc((size_t)NR_ * 2048 * 2);   // [hs | rel]
    ushort_t* A2       = (ushort_t*)alloc((size_t)NR_ * 2048 * 2);   // [ts | rel] (adjacent)
    ushort_t* Whb      = (ushort_t*)alloc((size_t)EMB_ * 2048 * 2);  // Wh^T bf16
    ushort_t* Wtb      = (ushort_t*)alloc((size_t)EMB_ * 2048 * 2);  // adjacent to Whb
    ushort_t* he_bf    = (ushort_t*)alloc((size_t)NR_ * EMB_ * 2);
    ushort_t* te_bf    = (ushort_t*)alloc((size_t)NR_ * EMB_ * 2);   // adjacent to he_bf
    ushort_t* Wbt      = (ushort_t*)alloc((size_t)EMB_ * KBIG_ * 2); // Wb^T bf16 [768][49152]

    const size_t slice_b = (size_t)NR_ * EMB_ * 4;
    int slices = (ws_size >= off + 8 * slice_b) ? 8 : 1;
    float* embedsN = (float*)alloc((size_t)slices * slice_b);

    // 1) transposed bf16 copies of weights / seq
    k_transpose_cvt<<<dim3(H_ / 64, L_ / 64, B_), 256, 0, stream>>>(seq, seq_t, L_, H_);
    k_transpose_cvt<<<dim3(EMB_ / 64, 2048 / 64, 1), 256, 0, stream>>>(Wh, Whb, 2048, EMB_);
    k_transpose_cvt<<<dim3(EMB_ / 64, 2048 / 64, 1), 256, 0, stream>>>(Wt, Wtb, 2048, EMB_);
    k_transpose_cvt<<<dim3(EMB_ / 64, KBIG_ / 64, 1), 256, 0, stream>>>(Wb, Wbt, KBIG_, EMB_);

    // 2) entity aggregation
    k_ent_emb<<<B_ * E_, 256, 0, stream>>>(entl, labels, ent_emb);
    k_ent_attn<<<B_ * E_ * NH_, 256, 0, stream>>>(attn, labels, ent_attn);

    // 3) pair attention rows + gathers
    k_ht<<<NR_, 256, 0, stream>>>(ent_attn, hts, ht_bf);
    k_gather<<<NR_, 256, 0, stream>>>(ent_emb, hts, A1, A2);

    // 4) rel = ht @ seq  (batched over B), written bf16 into cols 1024.. of A1 and A2
    k_gemm<false, false, true><<<dim3(H_ / 128, R_ / 128, B_), 256, 0, stream>>>(
        ht_bf, (long)R_ * L_, L_,
        seq_t, (long)H_ * L_, L_,
        L_, nullptr, nullptr,
        A1 + 1024, A2 + 1024, (long)R_ * 2048, 2048);

    // 5) he = tanh(A1 @ Wh + bh), te = tanh(A2 @ Wt + bt)   (z selects the pair)
    k_gemm<true, true, false><<<dim3(EMB_ / 128, NR_ / 128, 2), 256, 0, stream>>>(
        A1, (long)NR_ * 2048, 2048,
        Whb, (long)EMB_ * 2048, 2048,
        2048, bh, bt,
        he_bf, nullptr, (long)NR_ * EMB_, EMB_);

    // 6) embeds = bl @ Wb  (single-barrier staged K-loop; 8 K-slices XCD-mapped)
    if (slices == 1)
        (void)hipMemsetAsync(embedsN, 0, slice_b, stream);
    k_bilinear<<<768, 256, 0, stream>>>(he_bf, te_bf, Wbt, embedsN, slices);

    // 7) out = (sum_z embeds + bb) @ Wc + bc   (fp32)
    k_final<<<NR_, 128, 0, stream>>>(embedsN, slices, bb, Wc, bc, out);
}